// Round 9
// baseline (485.989 us; speedup 1.0000x reference)
//
#include <hip/hip_runtime.h>
#include <hip/hip_cooperative_groups.h>
#include <stdint.h>
#include <math.h>

namespace cg = cooperative_groups;

typedef __attribute__((ext_vector_type(8))) short short8;
typedef __attribute__((ext_vector_type(4))) float float4v;

__device__ __forceinline__ uint16_t f2bf(float f){
  union { float f; uint32_t i; } c; c.f = f;
  uint32_t r = c.i + 0x7fffu + ((c.i >> 16) & 1u);   // round-to-nearest-even
  return (uint16_t)(r >> 16);
}
__device__ __forceinline__ uint32_t pack2(float lo, float hi){
  return (uint32_t)f2bf(lo) | ((uint32_t)f2bf(hi) << 16);
}
__device__ __forceinline__ void acc_bf2(uint32_t w, float& x, float& y){
  union { uint32_t i; float f; } a, b;
  a.i = w << 16; b.i = w & 0xffff0000u;
  x += a.f; y += b.f;
}
__device__ __forceinline__ void accum8(uint4 v, float* a){
  acc_bf2(v.x, a[0], a[1]); acc_bf2(v.y, a[2], a[3]);
  acc_bf2(v.z, a[4], a[5]); acc_bf2(v.w, a[6], a[7]);
}

#define WT_STRIDE 136   // shorts per staged weight row (128 + 8 pad)

// ---------------------------------------------------------------------------
// Cooperative mega-kernel: prep -> build -> agg1 -> gemm1 -> agg2 -> gemm23
// with grid.sync() between phases (replaces 5 inter-kernel drains).
// Phase bodies are the r7-proven kernels re-indexed for 512-thr blocks.
// LDS: one 34816-B arena aliased per phase (max = gemm weight double-slab).
// __launch_bounds__(512,6): 24 waves/CU -> agg TLP ~= standalone (r0: 25).
// ---------------------------------------------------------------------------

struct MegaParams {
  const int* ei;
  const float *x, *W1l, *b1l, *W1r, *W2l, *b2l, *W2r, *W3l, *b3l, *W3r;
  float* out;
  int* fill; uint32_t* bins; uint32_t* esrc; int2* rowptr2;
  uint16_t *xb, *wb, *x1b, *agg;
  int E, n, NB, CAP, p1blk;
  size_t half;
};

__device__ __forceinline__ void agg_phase(const uint16_t* __restrict__ xin,
                                          const int2* __restrict__ rowptr2,
                                          const uint32_t* __restrict__ esrc,
                                          uint16_t* __restrict__ aggw,
                                          int n, int tid, int bid, int gsz){
  int wid = tid >> 6, lane = tid & 63;
  int sub = lane >> 4, fq = lane & 15;
  const uint4* xv = (const uint4*)xin;              // row = 16 x uint4 (256B)
  for (int node = bid * 8 + wid; node < n; node += gsz * 8){
    int2 be = rowptr2[node];
    int beg = be.x, end = be.y;
    float inv = 1.f / fmaxf((float)(end - beg), 1.f);
    float a[8] = {0.f,0.f,0.f,0.f,0.f,0.f,0.f,0.f};
    int e = beg + sub;
    for (; e + 12 < end; e += 16){
      int s0 = esrc[e], s1 = esrc[e + 4], s2 = esrc[e + 8], s3 = esrc[e + 12];
      uint4 v0 = xv[(size_t)s0 * 16 + fq];
      uint4 v1 = xv[(size_t)s1 * 16 + fq];
      uint4 v2 = xv[(size_t)s2 * 16 + fq];
      uint4 v3 = xv[(size_t)s3 * 16 + fq];
      accum8(v0, a); accum8(v1, a); accum8(v2, a); accum8(v3, a);
    }
    for (; e < end; e += 4){
      uint4 v = xv[(size_t)esrc[e] * 16 + fq];
      accum8(v, a);
    }
    #pragma unroll
    for (int i = 0; i < 8; ++i){
      a[i] += __shfl_xor(a[i], 16);
      a[i] += __shfl_xor(a[i], 32);
      a[i] *= inv;
    }
    if (sub == 0){
      uint4 o;
      o.x = pack2(a[0], a[1]); o.y = pack2(a[2], a[3]);
      o.z = pack2(a[4], a[5]); o.w = pack2(a[6], a[7]);
      ((uint4*)aggw)[(size_t)node * 16 + fq] = o;
    }
  }
}

__device__ __forceinline__ void stage_weights512(const uint16_t* __restrict__ Wl,
                                                 const uint16_t* __restrict__ Wr,
                                                 int ch, uint16_t* lds_l,
                                                 uint16_t* lds_r, int tid){
  const uint4* srcL = (const uint4*)(Wl + (size_t)(ch * 64) * 128);
  const uint4* srcR = (const uint4*)(Wr + (size_t)(ch * 64) * 128);
  #pragma unroll
  for (int i = 0; i < 2; ++i){          // 1024 uint4 per matrix / 512 thr
    int j = tid + i * 512;
    int row = j >> 4, c8 = j & 15;
    uint4 vl = srcL[j], vr = srcR[j];
    *(uint4*)(lds_l + row * WT_STRIDE + c8 * 8) = vl;
    *(uint4*)(lds_r + row * WT_STRIDE + c8 * 8) = vr;
  }
}

__global__ __launch_bounds__(512, 6) void mega_kernel(MegaParams P){
  cg::grid_group gg = cg::this_grid();
  __shared__ __align__(16) uint8_t smem[34816];
  const int tid = threadIdx.x, bid = blockIdx.x, gsz = gridDim.x;
  const int WSZ = 128 * 128;

  // ---- phase P: LDS-staged bucket binning + bf16 conversions ---------------
  if (bid < P.p1blk){
    int* hist = (int*)smem;            // [256]
    int* scn  = hist + 256;
    int* cur  = hist + 512;
    int* gbas = hist + 768;
    int* excl = hist + 1024;
    uint32_t* stg = (uint32_t*)(smem + 5120);   // [4096]
    if (tid < 256) hist[tid] = 0;
    __syncthreads();
    int e0 = bid * 4096;
    int nval = P.E - e0; if (nval > 4096) nval = 4096;
    uint32_t w[8]; int bk[8];
    #pragma unroll
    for (int k = 0; k < 8; ++k){
      int e = e0 + k * 512 + tid;
      bool ok = e < P.E;
      int s = ok ? P.ei[e] : 0;
      int d = ok ? P.ei[P.E + e] : 0;
      w[k] = (uint32_t)s | ((uint32_t)d << 16);
      bk[k] = ok ? (d >> 8) : -1;
      if (ok) atomicAdd(&hist[bk[k]], 1);
    }
    __syncthreads();
    if (tid < 256) scn[tid] = hist[tid];
    __syncthreads();
    #pragma unroll
    for (int off = 1; off < 256; off <<= 1){
      int v = 0;
      if (tid < 256 && tid >= off) v = scn[tid - off];
      __syncthreads();
      if (tid < 256) scn[tid] += v;
      __syncthreads();
    }
    if (tid < 256){
      int ex = scn[tid] - hist[tid];
      excl[tid] = ex; cur[tid] = ex;
      gbas[tid] = (tid < P.NB && hist[tid] > 0)
                  ? atomicAdd(&P.fill[tid], hist[tid]) : 0;
    }
    __syncthreads();
    #pragma unroll
    for (int k = 0; k < 8; ++k){
      if (bk[k] >= 0){
        int p = atomicAdd(&cur[bk[k]], 1);
        stg[p] = w[k];
      }
    }
    __syncthreads();
    for (int i = tid; i < nval; i += 512){
      uint32_t v = stg[i];
      int b = v >> 24;                  // dst>>8 (dst<65536)
      int loc = gbas[b] + (i - excl[b]);
      if (loc < P.CAP)
        __builtin_nontemporal_store(v, P.bins + (size_t)b * P.CAP + loc);
    }
  } else {
    int i0 = (bid - P.p1blk) * 512 + tid;
    int stride = (gsz - P.p1blk) * 512;
    int nx4 = (P.n * 128) >> 2;
    for (int j = i0; j < nx4; j += stride){
      float4 v = ((const float4*)P.x)[j];
      uint2 o; o.x = pack2(v.x, v.y); o.y = pack2(v.z, v.w);
      ((uint2*)P.xb)[j] = o;
    }
    for (int j = i0; j < 6 * WSZ; j += stride){
      int t = j >> 14, o = j & (WSZ - 1);
      const float* w = t == 0 ? P.W1l : t == 1 ? P.W1r : t == 2 ? P.W2l
                     : t == 3 ? P.W2r : t == 4 ? P.W3l : P.W3r;
      P.wb[j] = f2bf(w[o]);
    }
  }
  gg.sync();

  // ---- phase B: per-bucket CSR (LDS reorder + coalesced dump) --------------
  for (int b = bid; b < P.NB; b += gsz){
    int* hist = (int*)smem; int* scn = hist + 256; int* cursor = hist + 512;
    uint32_t* stage = (uint32_t*)(smem + 3072);   // [5120]
    int cnt = P.fill[b]; if (cnt > P.CAP) cnt = P.CAP;
    size_t gb = (size_t)b * P.CAP;
    if (tid < 256) hist[tid] = 0;
    __syncthreads();
    for (int i = tid; i < cnt; i += 512)
      atomicAdd(&hist[(P.bins[gb + i] >> 16) & 255], 1);
    __syncthreads();
    if (tid < 256) scn[tid] = hist[tid];
    __syncthreads();
    #pragma unroll
    for (int off = 1; off < 256; off <<= 1){
      int v = 0;
      if (tid < 256 && tid >= off) v = scn[tid - off];
      __syncthreads();
      if (tid < 256) scn[tid] += v;
      __syncthreads();
    }
    if (tid < 256){
      int ex = scn[tid] - hist[tid];
      cursor[tid] = ex;
      int node = (b << 8) + tid;
      if (node < P.n) P.rowptr2[node] = make_int2((int)gb + ex, (int)gb + scn[tid]);
    }
    __syncthreads();
    for (int i = tid; i < cnt; i += 512){
      uint32_t v = P.bins[gb + i];
      int p = atomicAdd(&cursor[(v >> 16) & 255], 1);
      stage[p] = v & 0xffffu;
    }
    __syncthreads();
    for (int i = tid; i < cnt; i += 512)
      __builtin_nontemporal_store(stage[i], P.esrc + gb + i);
    __syncthreads();
  }
  gg.sync();

  // ---- phase A1: aggregate x -> agg ----------------------------------------
  agg_phase(P.xb, P.rowptr2, P.esrc, P.agg, P.n, tid, bid, gsz);
  gg.sync();

  // ---- phase G1: x1 = relu(agg@W1l^T + b1 + x@W1r^T) -----------------------
  {
    uint16_t* lds_l = (uint16_t*)smem;
    uint16_t* lds_r = lds_l + 64 * WT_STRIDE;
    int lane = tid & 63, wid = tid >> 6;
    int m = lane & 15, quad = lane >> 4;
    const uint16_t* Wl = P.wb;            // W1l
    const uint16_t* Wr = P.wb + WSZ;      // W1r
    int ngt = (P.n + 63) >> 6;            // 64-row tiles
    int nt2 = (ngt + 1) >> 1;             // 2 tiles per block (8 waves)
    for (int t2 = bid; t2 < nt2; t2 += gsz){
      int tile = t2 * 2 + (wid >> 2);
      int r0 = tile * 64 + (wid & 3) * 16;
      int arow = r0 + m; if (arow > P.n - 1) arow = P.n - 1;
      short8 a0f[4], a1f[4];
      #pragma unroll
      for (int ks = 0; ks < 4; ++ks){
        a0f[ks] = *(const short8*)(P.agg + (size_t)arow * 128 + ks * 32 + quad * 8);
        a1f[ks] = *(const short8*)(P.xb  + (size_t)arow * 128 + ks * 32 + quad * 8);
      }
      for (int ch = 0; ch < 2; ++ch){
        __syncthreads();
        stage_weights512(Wl, Wr, ch, lds_l, lds_r, tid);
        __syncthreads();
        float4v acc[4];
        #pragma unroll
        for (int ct = 0; ct < 4; ++ct) acc[ct] = (float4v){0.f, 0.f, 0.f, 0.f};
        #pragma unroll
        for (int ks = 0; ks < 4; ++ks){
          #pragma unroll
          for (int ct = 0; ct < 4; ++ct){
            short8 b0 = *(const short8*)(lds_l + (ct * 16 + m) * WT_STRIDE + ks * 32 + quad * 8);
            acc[ct] = __builtin_amdgcn_mfma_f32_16x16x32_bf16(a0f[ks], b0, acc[ct], 0, 0, 0);
            short8 b1 = *(const short8*)(lds_r + (ct * 16 + m) * WT_STRIDE + ks * 32 + quad * 8);
            acc[ct] = __builtin_amdgcn_mfma_f32_16x16x32_bf16(a1f[ks], b1, acc[ct], 0, 0, 0);
          }
        }
        #pragma unroll
        for (int ct = 0; ct < 4; ++ct){
          int col = ch * 64 + ct * 16 + m;
          float bv = P.b1l[col];
          #pragma unroll
          for (int i = 0; i < 4; ++i){
            int grow = r0 + quad * 4 + i;
            if (grow < P.n)
              P.x1b[(size_t)grow * 128 + col] = f2bf(fmaxf(acc[ct][i] + bv, 0.f));
          }
        }
      }
    }
  }
  gg.sync();

  // ---- phase A2: aggregate x1 -> agg ---------------------------------------
  agg_phase(P.x1b, P.rowptr2, P.esrc, P.agg, P.n, tid, bid, gsz);
  gg.sync();

  // ---- phase G23: two output passes (W2 -> out[0], W3 -> out[half]) --------
  {
    uint16_t* lds_l = (uint16_t*)smem;
    uint16_t* lds_r = lds_l + 64 * WT_STRIDE;
    int lane = tid & 63, wid = tid >> 6;
    int m = lane & 15, quad = lane >> 4;
    int ngt = (P.n + 63) >> 6;
    int nt2 = (ngt + 1) >> 1;
    for (int t2 = bid; t2 < nt2; t2 += gsz){
      int tile = t2 * 2 + (wid >> 2);
      int r0 = tile * 64 + (wid & 3) * 16;
      int arow = r0 + m; if (arow > P.n - 1) arow = P.n - 1;
      short8 a0f[4], a1f[4];
      #pragma unroll
      for (int ks = 0; ks < 4; ++ks){
        a0f[ks] = *(const short8*)(P.agg + (size_t)arow * 128 + ks * 32 + quad * 8);
        a1f[ks] = *(const short8*)(P.x1b + (size_t)arow * 128 + ks * 32 + quad * 8);
      }
      for (int idx = 0; idx < 4; ++idx){
        int pass = idx >> 1, ch = idx & 1;
        const uint16_t* Wl = P.wb + (pass ? 4 : 2) * WSZ;
        const uint16_t* Wr = P.wb + (pass ? 5 : 3) * WSZ;
        __syncthreads();
        stage_weights512(Wl, Wr, ch, lds_l, lds_r, tid);
        __syncthreads();
        float4v acc[4];
        #pragma unroll
        for (int ct = 0; ct < 4; ++ct) acc[ct] = (float4v){0.f, 0.f, 0.f, 0.f};
        #pragma unroll
        for (int ks = 0; ks < 4; ++ks){
          #pragma unroll
          for (int ct = 0; ct < 4; ++ct){
            short8 b0 = *(const short8*)(lds_l + (ct * 16 + m) * WT_STRIDE + ks * 32 + quad * 8);
            acc[ct] = __builtin_amdgcn_mfma_f32_16x16x32_bf16(a0f[ks], b0, acc[ct], 0, 0, 0);
            short8 b1 = *(const short8*)(lds_r + (ct * 16 + m) * WT_STRIDE + ks * 32 + quad * 8);
            acc[ct] = __builtin_amdgcn_mfma_f32_16x16x32_bf16(a1f[ks], b1, acc[ct], 0, 0, 0);
          }
        }
        const float* bb = pass ? P.b3l : P.b2l;
        float* op = P.out + (pass ? P.half : 0);
        #pragma unroll
        for (int ct = 0; ct < 4; ++ct){
          int col = ch * 64 + ct * 16 + m;
          float bv = bb[col];
          #pragma unroll
          for (int i = 0; i < 4; ++i){
            int grow = r0 + quad * 4 + i;
            if (grow < P.n)
              __builtin_nontemporal_store(acc[ct][i] + bv,
                                          op + (size_t)grow * 128 + col);
          }
        }
      }
    }
  }
}

// ---------------------------------------------------------------------------
// Fallback path: the r7 six-kernel pipeline (used if cooperative launch is
// rejected by the runtime / capture). Verbatim r7.
// ---------------------------------------------------------------------------

__global__ __launch_bounds__(512) void prep_kernel(
    const int* __restrict__ ei, int E, int NB, int CAP, int p1blk,
    int* __restrict__ fill, uint32_t* __restrict__ bins,
    const float* __restrict__ x,
    const float* __restrict__ w0, const float* __restrict__ w1,
    const float* __restrict__ w2, const float* __restrict__ w3,
    const float* __restrict__ w4, const float* __restrict__ w5,
    uint16_t* __restrict__ xb, uint16_t* __restrict__ wb, int nx){
  if ((int)blockIdx.x < p1blk){
    __shared__ int hist[256], scn[256], cursor[256], gbase[256], excl[256];
    __shared__ uint32_t stage[4096];
    int tid = threadIdx.x;
    if (tid < 256) hist[tid] = 0;
    __syncthreads();
    int e0 = blockIdx.x * 4096;
    int nval = E - e0; if (nval > 4096) nval = 4096;
    uint32_t w[8]; int bk[8];
    #pragma unroll
    for (int k = 0; k < 8; ++k){
      int e = e0 + k * 512 + tid;
      bool ok = e < E;
      int s = ok ? ei[e] : 0;
      int d = ok ? ei[E + e] : 0;
      w[k] = (uint32_t)s | ((uint32_t)d << 16);
      bk[k] = ok ? (d >> 8) : -1;
      if (ok) atomicAdd(&hist[bk[k]], 1);
    }
    __syncthreads();
    if (tid < 256) scn[tid] = hist[tid];
    __syncthreads();
    #pragma unroll
    for (int off = 1; off < 256; off <<= 1){
      int v = 0;
      if (tid < 256 && tid >= off) v = scn[tid - off];
      __syncthreads();
      if (tid < 256) scn[tid] += v;
      __syncthreads();
    }
    if (tid < 256){
      int ex = scn[tid] - hist[tid];
      excl[tid] = ex; cursor[tid] = ex;
      gbase[tid] = (tid < NB && hist[tid] > 0)
                   ? atomicAdd(&fill[tid], hist[tid]) : 0;
    }
    __syncthreads();
    #pragma unroll
    for (int k = 0; k < 8; ++k){
      if (bk[k] >= 0){
        int p = atomicAdd(&cursor[bk[k]], 1);
        stage[p] = w[k];
      }
    }
    __syncthreads();
    for (int i = tid; i < nval; i += 512){
      uint32_t v = stage[i];
      int b = v >> 24;
      int loc = gbase[b] + (i - excl[b]);
      if (loc < CAP)
        __builtin_nontemporal_store(v, bins + (size_t)b * CAP + loc);
    }
  } else {
    int i = (blockIdx.x - p1blk) * 512 + threadIdx.x;
    int stride = (gridDim.x - p1blk) * 512;
    for (int j = i; j < (nx >> 2); j += stride){
      float4 v = ((const float4*)x)[j];
      uint2 o;
      o.x = pack2(v.x, v.y); o.y = pack2(v.z, v.w);
      ((uint2*)xb)[j] = o;
    }
    const int WSZ = 128 * 128;
    for (int j = i; j < 6 * WSZ; j += stride){
      int t = j >> 14, o = j & (WSZ - 1);
      const float* w = t == 0 ? w0 : t == 1 ? w1 : t == 2 ? w2 : t == 3 ? w3 : t == 4 ? w4 : w5;
      wb[j] = f2bf(w[o]);
    }
  }
}

__global__ __launch_bounds__(512) void build_kernel(const uint32_t* __restrict__ bins,
                                                    const int* __restrict__ fill,
                                                    int CAP, int n,
                                                    int2* __restrict__ rowptr2,
                                                    uint32_t* __restrict__ esrc){
  __shared__ int hist[256], scn[256], cursor[256];
  __shared__ uint32_t stage[5120];
  int b = blockIdx.x, tid = threadIdx.x;
  int cnt = fill[b]; if (cnt > CAP) cnt = CAP;
  size_t gb = (size_t)b * CAP;
  if (tid < 256) hist[tid] = 0;
  __syncthreads();
  for (int i = tid; i < cnt; i += 512)
    atomicAdd(&hist[(bins[gb + i] >> 16) & 255], 1);
  __syncthreads();
  if (tid < 256) scn[tid] = hist[tid];
  __syncthreads();
  #pragma unroll
  for (int off = 1; off < 256; off <<= 1){
    int v = 0;
    if (tid < 256 && tid >= off) v = scn[tid - off];
    __syncthreads();
    if (tid < 256) scn[tid] += v;
    __syncthreads();
  }
  if (tid < 256){
    int ex = scn[tid] - hist[tid];
    cursor[tid] = ex;
    int node = (b << 8) + tid;
    if (node < n) rowptr2[node] = make_int2((int)gb + ex, (int)gb + scn[tid]);
  }
  __syncthreads();
  for (int i = tid; i < cnt; i += 512){
    uint32_t v = bins[gb + i];
    int p = atomicAdd(&cursor[(v >> 16) & 255], 1);
    stage[p] = v & 0xffffu;
  }
  __syncthreads();
  for (int i = tid; i < cnt; i += 512)
    __builtin_nontemporal_store(stage[i], esrc + gb + i);
}

__global__ __launch_bounds__(256) void agg_kernel(const uint16_t* __restrict__ xin,
                                                  const int2* __restrict__ rowptr2,
                                                  const uint32_t* __restrict__ esrc,
                                                  uint16_t* __restrict__ aggw, int n){
  int node = blockIdx.x * 4 + (threadIdx.x >> 6);
  if (node >= n) return;
  int lane = threadIdx.x & 63;
  int sub = lane >> 4, fq = lane & 15;
  const uint4* xv = (const uint4*)xin;
  int2 be = rowptr2[node];
  int beg = be.x, end = be.y;
  float inv = 1.f / fmaxf((float)(end - beg), 1.f);
  float a[8] = {0.f,0.f,0.f,0.f,0.f,0.f,0.f,0.f};
  int e = beg + sub;
  for (; e + 12 < end; e += 16){
    int s0 = esrc[e], s1 = esrc[e + 4], s2 = esrc[e + 8], s3 = esrc[e + 12];
    uint4 v0 = xv[(size_t)s0 * 16 + fq];
    uint4 v1 = xv[(size_t)s1 * 16 + fq];
    uint4 v2 = xv[(size_t)s2 * 16 + fq];
    uint4 v3 = xv[(size_t)s3 * 16 + fq];
    accum8(v0, a); accum8(v1, a); accum8(v2, a); accum8(v3, a);
  }
  for (; e < end; e += 4){
    uint4 v = xv[(size_t)esrc[e] * 16 + fq];
    accum8(v, a);
  }
  #pragma unroll
  for (int i = 0; i < 8; ++i){
    a[i] += __shfl_xor(a[i], 16);
    a[i] += __shfl_xor(a[i], 32);
    a[i] *= inv;
  }
  if (sub == 0){
    uint4 o;
    o.x = pack2(a[0], a[1]); o.y = pack2(a[2], a[3]);
    o.z = pack2(a[4], a[5]); o.w = pack2(a[6], a[7]);
    ((uint4*)aggw)[(size_t)node * 16 + fq] = o;
  }
}

__device__ __forceinline__ void stage_weights(const uint16_t* __restrict__ Wl,
                                              const uint16_t* __restrict__ Wr,
                                              int ch, uint16_t* lds_l,
                                              uint16_t* lds_r, int tid){
  const uint4* srcL = (const uint4*)(Wl + (size_t)(ch * 64) * 128);
  const uint4* srcR = (const uint4*)(Wr + (size_t)(ch * 64) * 128);
  #pragma unroll
  for (int i = 0; i < 4; ++i){
    int j = tid + i * 256;
    int row = j >> 4, c8 = j & 15;
    uint4 vl = srcL[j], vr = srcR[j];
    *(uint4*)(lds_l + row * WT_STRIDE + c8 * 8) = vl;
    *(uint4*)(lds_r + row * WT_STRIDE + c8 * 8) = vr;
  }
}

__global__ __launch_bounds__(256) void gemm1_kernel(
    const uint16_t* __restrict__ Aagg, const uint16_t* __restrict__ Ax,
    const uint16_t* __restrict__ Wl, const uint16_t* __restrict__ Wr,
    const float* __restrict__ bias, uint16_t* __restrict__ x1b, int n){
  __shared__ uint16_t lds_l[64 * WT_STRIDE], lds_r[64 * WT_STRIDE];
  int tid = threadIdx.x, lane = tid & 63, wid = tid >> 6;
  int m = lane & 15, quad = lane >> 4;
  int r0 = blockIdx.x * 64 + wid * 16;
  int arow = r0 + m; if (arow > n - 1) arow = n - 1;
  short8 a0f[4], a1f[4];
  #pragma unroll
  for (int ks = 0; ks < 4; ++ks){
    a0f[ks] = *(const short8*)(Aagg + (size_t)arow * 128 + ks * 32 + quad * 8);
    a1f[ks] = *(const short8*)(Ax   + (size_t)arow * 128 + ks * 32 + quad * 8);
  }
  for (int ch = 0; ch < 2; ++ch){
    if (ch) __syncthreads();
    stage_weights(Wl, Wr, ch, lds_l, lds_r, tid);
    __syncthreads();
    float4v acc[4];
    #pragma unroll
    for (int ct = 0; ct < 4; ++ct) acc[ct] = (float4v){0.f, 0.f, 0.f, 0.f};
    #pragma unroll
    for (int ks = 0; ks < 4; ++ks){
      #pragma unroll
      for (int ct = 0; ct < 4; ++ct){
        short8 b0 = *(const short8*)(lds_l + (ct * 16 + m) * WT_STRIDE + ks * 32 + quad * 8);
        acc[ct] = __builtin_amdgcn_mfma_f32_16x16x32_bf16(a0f[ks], b0, acc[ct], 0, 0, 0);
        short8 b1 = *(const short8*)(lds_r + (ct * 16 + m) * WT_STRIDE + ks * 32 + quad * 8);
        acc[ct] = __builtin_amdgcn_mfma_f32_16x16x32_bf16(a1f[ks], b1, acc[ct], 0, 0, 0);
      }
    }
    #pragma unroll
    for (int ct = 0; ct < 4; ++ct){
      int col = ch * 64 + ct * 16 + m;
      float bv = bias[col];
      #pragma unroll
      for (int i = 0; i < 4; ++i){
        int grow = r0 + quad * 4 + i;
        if (grow < n)
          x1b[(size_t)grow * 128 + col] = f2bf(fmaxf(acc[ct][i] + bv, 0.f));
      }
    }
  }
}

__global__ __launch_bounds__(256) void gemm23_kernel(
    const uint16_t* __restrict__ Aagg, const uint16_t* __restrict__ Ax,
    const uint16_t* __restrict__ W2l, const uint16_t* __restrict__ W2r,
    const float* __restrict__ b2,
    const uint16_t* __restrict__ W3l, const uint16_t* __restrict__ W3r,
    const float* __restrict__ b3,
    float* __restrict__ out, size_t half, int n){
  __shared__ uint16_t lds_l[64 * WT_STRIDE], lds_r[64 * WT_STRIDE];
  int tid = threadIdx.x, lane = tid & 63, wid = tid >> 6;
  int m = lane & 15, quad = lane >> 4;
  int r0 = blockIdx.x * 64 + wid * 16;
  int arow = r0 + m; if (arow > n - 1) arow = n - 1;
  short8 a0f[4], a1f[4];
  #pragma unroll
  for (int ks = 0; ks < 4; ++ks){
    a0f[ks] = *(const short8*)(Aagg + (size_t)arow * 128 + ks * 32 + quad * 8);
    a1f[ks] = *(const short8*)(Ax   + (size_t)arow * 128 + ks * 32 + quad * 8);
  }
  for (int idx = 0; idx < 4; ++idx){
    int pass = idx >> 1, ch = idx & 1;
    if (idx) __syncthreads();
    stage_weights(pass ? W3l : W2l, pass ? W3r : W2r, ch, lds_l, lds_r, tid);
    __syncthreads();
    float4v acc[4];
    #pragma unroll
    for (int ct = 0; ct < 4; ++ct) acc[ct] = (float4v){0.f, 0.f, 0.f, 0.f};
    #pragma unroll
    for (int ks = 0; ks < 4; ++ks){
      #pragma unroll
      for (int ct = 0; ct < 4; ++ct){
        short8 b0 = *(const short8*)(lds_l + (ct * 16 + m) * WT_STRIDE + ks * 32 + quad * 8);
        acc[ct] = __builtin_amdgcn_mfma_f32_16x16x32_bf16(a0f[ks], b0, acc[ct], 0, 0, 0);
        short8 b1 = *(const short8*)(lds_r + (ct * 16 + m) * WT_STRIDE + ks * 32 + quad * 8);
        acc[ct] = __builtin_amdgcn_mfma_f32_16x16x32_bf16(a1f[ks], b1, acc[ct], 0, 0, 0);
      }
    }
    const float* bb = pass ? b3 : b2;
    float* op = out + (pass ? half : 0);
    #pragma unroll
    for (int ct = 0; ct < 4; ++ct){
      int col = ch * 64 + ct * 16 + m;
      float bv = bb[col];
      #pragma unroll
      for (int i = 0; i < 4; ++i){
        int grow = r0 + quad * 4 + i;
        if (grow < n)
          __builtin_nontemporal_store(acc[ct][i] + bv,
                                      op + (size_t)grow * 128 + col);
      }
    }
  }
}

// ---- launcher --------------------------------------------------------------

extern "C" void kernel_launch(void* const* d_in, const int* in_sizes, int n_in,
                              void* d_out, int out_size, void* d_ws, size_t ws_size,
                              hipStream_t stream) {
  const float* x   = (const float*)d_in[0];   // fp32 [N,128]
  const int*   ei  = (const int*)d_in[1];     // int32 [2,E]
  const float* W1l = (const float*)d_in[2];
  const float* b1l = (const float*)d_in[3];
  const float* W1r = (const float*)d_in[4];
  const float* W2l = (const float*)d_in[5];
  const float* b2l = (const float*)d_in[6];
  const float* W2r = (const float*)d_in[7];
  const float* W3l = (const float*)d_in[8];
  const float* b3l = (const float*)d_in[9];
  const float* W3r = (const float*)d_in[10];
  float* out = (float*)d_out;

  const int n = in_sizes[0] / 128;
  const int E = in_sizes[1] / 2;
  const size_t half = (size_t)n * 128;
  const int WSZ = 128 * 128;

  const int NB = (n + 255) >> 8;
  int mean = (E + NB - 1) / NB;
  int CAP = mean + 8 * (int)sqrt((double)mean) + 64;
  CAP = (CAP + 63) & ~63;
  if (CAP > 5120) CAP = 5120;

  size_t off = 0;
  auto carve = [&](size_t bytes) -> void* {
    void* p = (char*)d_ws + off;
    off += (bytes + 255) & ~(size_t)255;
    return p;
  };
  int2*     rowptr2 = (int2*)carve((size_t)n * 8);
  int*      fill    = (int*)carve((size_t)NB * 4);
  uint32_t* esrc    = (uint32_t*)carve((size_t)NB * CAP * 4);
  uint16_t* xb      = (uint16_t*)carve(half * 2);
  uint16_t* wb      = (uint16_t*)carve((size_t)6 * WSZ * 2);
  uint16_t* x1b     = (uint16_t*)carve(half * 2);
  uint16_t* agg     = (uint16_t*)carve(half * 2);
  uint32_t* bins    = (uint32_t*)carve((size_t)NB * CAP * 4);
  (void)ws_size;

  hipMemsetAsync(fill, 0, (size_t)NB * 4, stream);

  int p1blk = (E + 4095) / 4096;

  // ---- cooperative mega-kernel path ----
  static int grid = 0;
  if (grid == 0){
    int perCU = 0;
    if (hipOccupancyMaxActiveBlocksPerMultiprocessor(&perCU,
            (const void*)mega_kernel, 512, 0) != hipSuccess || perCU < 1)
      perCU = 1;
    grid = perCU * 256;                 // 256 CUs on MI355X
    if (grid > 1024) grid = 1024;
    if (grid < 256)  grid = 256;
  }

  MegaParams mp;
  mp.ei = ei; mp.x = x;
  mp.W1l = W1l; mp.b1l = b1l; mp.W1r = W1r;
  mp.W2l = W2l; mp.b2l = b2l; mp.W2r = W2r;
  mp.W3l = W3l; mp.b3l = b3l; mp.W3r = W3r;
  mp.out = out;
  mp.fill = fill; mp.bins = bins; mp.esrc = esrc; mp.rowptr2 = rowptr2;
  mp.xb = xb; mp.wb = wb; mp.x1b = x1b; mp.agg = agg;
  mp.E = E; mp.n = n; mp.NB = NB; mp.CAP = CAP; mp.p1blk = p1blk;
  mp.half = half;

  void* args[] = { &mp };
  hipError_t err = hipLaunchCooperativeKernel((const void*)mega_kernel,
                                              dim3(grid), dim3(512),
                                              args, 0, stream);
  if (err == hipSuccess) return;

  // ---- fallback: r7 six-kernel pipeline ----
  int cblk = 512;
  prep_kernel<<<p1blk + cblk, 512, 0, stream>>>(ei, E, NB, CAP, p1blk, fill, bins,
                                                x, W1l, W1r, W2l, W2r, W3l, W3r,
                                                xb, wb, (int)half);
  build_kernel<<<NB, 512, 0, stream>>>(bins, fill, CAP, n, rowptr2, esrc);

  int ablk = (n + 3) / 4;
  int gblk = (n + 63) / 64;
  const uint16_t *Wb1l = wb, *Wb1r = wb + WSZ, *Wb2l = wb + 2 * WSZ,
                 *Wb2r = wb + 3 * WSZ, *Wb3l = wb + 4 * WSZ, *Wb3r = wb + 5 * WSZ;

  agg_kernel<<<ablk, 256, 0, stream>>>(xb, rowptr2, esrc, agg, n);
  gemm1_kernel<<<gblk, 256, 0, stream>>>(agg, xb, Wb1l, Wb1r, b1l, x1b, n);
  agg_kernel<<<ablk, 256, 0, stream>>>(x1b, rowptr2, esrc, agg, n);
  gemm23_kernel<<<gblk, 256, 0, stream>>>(agg, x1b, Wb2l, Wb2r, b2l,
                                          Wb3l, Wb3r, b3l, out, half, n);
}